// Round 3
// baseline (482.227 us; speedup 1.0000x reference)
//
#include <hip/hip_runtime.h>

// Problem constants (fixed by the reference)
#define N_IMG 8
#define C_CLS 19
#define H_DIM 512
#define W_DIM 1024
#define HW (H_DIM * W_DIM)              // 524288 pixels per image
#define HW2 (HW / 2)                    // 262144 float2 groups per channel
#define TOTAL_ELEMS (N_IMG * C_CLS * HW)
#define RATIO 0.2f

#define BT 256
#define BLOCKS_X (HW2 / BT)             // 1024 blocks per image, exact cover

// Pass 1: per-image per-class sum of p^2 (Q) and argmax histogram (Hist).
// KEY (round 2 lesson): __launch_bounds__(256,8) capped VGPRs at 64; compiler
// allocated 28 and REMATERIALIZED the 19-channel payload (re-reading L2 in
// every pass) -> latency-serialized at 1.6 TB/s. Cap 128 instead: the float2
// payload (38 VGPRs) + temps stays register-resident; 19 loads per thread all
// in flight once; HW still grants ~6 waves/SIMD at ~80 VGPRs.
__global__ __launch_bounds__(BT, 4) void iw_pass1(
    const float* __restrict__ in,   // (N, C, H, W)
    float* __restrict__ Q,          // [N_IMG * C_CLS], pre-zeroed
    int* __restrict__ Hist)         // [N_IMG * C_CLS], pre-zeroed
{
    const int n   = blockIdx.y;
    const int tid = threadIdx.x;
    const int i   = blockIdx.x * BT + tid;       // float2 index in plane
    const float2* base2 = reinterpret_cast<const float2*>(in + (size_t)n * C_CLS * HW);

    // 19 independent 8B/lane loads, all in flight together
    float2 x[C_CLS];
#pragma unroll
    for (int c = 0; c < C_CLS; ++c)
        x[c] = base2[(size_t)c * HW2 + i];

    int am0, am1;
    float inv0, inv1;
    {   // component 0: argmax (first index on ties) + softmax denom; e^2 in place
        float m = x[0].x; int a = 0;
#pragma unroll
        for (int c = 1; c < C_CLS; ++c) { if (x[c].x > m) { m = x[c].x; a = c; } }
        am0 = a;
        float S = 0.0f;
#pragma unroll
        for (int c = 0; c < C_CLS; ++c) { float e = __expf(x[c].x - m); S += e; x[c].x = e * e; }
        inv0 = __builtin_amdgcn_rcpf(S * S);
    }
    {   // component 1
        float m = x[0].y; int a = 0;
#pragma unroll
        for (int c = 1; c < C_CLS; ++c) { if (x[c].y > m) { m = x[c].y; a = c; } }
        am1 = a;
        float S = 0.0f;
#pragma unroll
        for (int c = 0; c < C_CLS; ++c) { float e = __expf(x[c].y - m); S += e; x[c].y = e * e; }
        inv1 = __builtin_amdgcn_rcpf(S * S);
    }

    __shared__ float qs[C_CLS][BT / 4 + 1];   // 19 x 65 floats = 4.9 KB
    __shared__ int   hs[4][C_CLS];

    // per-thread q_c; 2 DPP shuffle steps; every 4th lane parks the partial
#pragma unroll
    for (int c = 0; c < C_CLS; ++c) {
        float v = fmaf(x[c].y, inv1, x[c].x * inv0);
        v += __shfl_xor(v, 1, 64);
        v += __shfl_xor(v, 2, 64);
        if ((tid & 3) == 0) qs[c][tid >> 2] = v;
    }

    // histogram via wave ballot: transient scalar counts, no VGPR accumulators
    const int wave = tid >> 6, lane = tid & 63;
#pragma unroll
    for (int c = 0; c < C_CLS; ++c) {
        int cnt = (int)__popcll(__ballot(am0 == c))
                + (int)__popcll(__ballot(am1 == c));
        if (lane == 0) hs[wave][c] = cnt;
    }
    __syncthreads();

    // 152 threads: class c = t>>3, slot s = t&7 sums 8 entries, then 3 shuffles
    if (tid < 8 * C_CLS) {
        const int c = tid >> 3, s = tid & 7;
        float v = 0.0f;
#pragma unroll
        for (int j = 0; j < 8; ++j) v += qs[c][s * 8 + j];
        v += __shfl_xor(v, 1, 64);
        v += __shfl_xor(v, 2, 64);
        v += __shfl_xor(v, 4, 64);
        if (s == 0) atomicAdd(&Q[n * C_CLS + c], v);
    }
    if (tid < C_CLS) {
        int hv = hs[0][tid] + hs[1][tid] + hs[2][tid] + hs[3][tid];
        atomicAdd(&Hist[n * C_CLS + tid], hv);
    }
}

// Pass 2: weights from histogram, dot with Q, write scalar mean loss.
__global__ __launch_bounds__(64) void iw_pass2(
    const float* __restrict__ Q,
    const int* __restrict__ Hist,
    float* __restrict__ out)
{
    const int t = threadIdx.x;
    float loss = 0.0f;
    if (t < N_IMG) {
        float h[C_CLS];
        float hsum = 0.0f;
#pragma unroll
        for (int c = 0; c < C_CLS; ++c) {
            float v = (float)Hist[t * C_CLS + c];
            v = (v == 0.0f) ? 1.0f : v;                  // hist[hist==0] = 1
            h[c] = v;
            hsum += v;                                   // sum AFTER replacement
        }
#pragma unroll
        for (int c = 0; c < C_CLS; ++c) {
            float w = powf(hsum / h[c], RATIO);
            loss = fmaf(w, Q[t * C_CLS + c], loss);
        }
    }
    // reduce the 8 per-image values (lanes 8..63 contribute 0)
    loss += __shfl_xor(loss, 1, 64);
    loss += __shfl_xor(loss, 2, 64);
    loss += __shfl_xor(loss, 4, 64);
    if (t == 0)
        out[0] = -loss / (float)TOTAL_ELEMS;
}

extern "C" void kernel_launch(void* const* d_in, const int* in_sizes, int n_in,
                              void* d_out, int out_size, void* d_ws, size_t ws_size,
                              hipStream_t stream)
{
    const float* in = (const float*)d_in[0];
    float* out = (float*)d_out;

    // workspace layout: Q (float[152]) then Hist (int[152])
    float* Q  = (float*)d_ws;
    int* Hist = (int*)((char*)d_ws + N_IMG * C_CLS * sizeof(float));

    hipMemsetAsync(d_ws, 0, N_IMG * C_CLS * (sizeof(float) + sizeof(int)), stream);

    dim3 grid(BLOCKS_X, N_IMG);
    iw_pass1<<<grid, BT, 0, stream>>>(in, Q, Hist);
    iw_pass2<<<1, 64, 0, stream>>>(Q, Hist, out);
}

// Round 4
// 434.013 us; speedup vs baseline: 1.1111x; 1.1111x over previous
//
#include <hip/hip_runtime.h>

// Problem constants (fixed by the reference)
#define N_IMG 8
#define C_CLS 19
#define H_DIM 512
#define W_DIM 1024
#define HW (H_DIM * W_DIM)              // 524288 pixels per image
#define HW4 (HW / 4)                    // 131072 float4 groups per channel
#define TOTAL_ELEMS (N_IMG * C_CLS * HW)
#define RATIO 0.2f

#define BT 256
#define BLOCKS_X (HW4 / BT)             // 512 blocks per image, exact cover

__device__ __forceinline__ float& f4c(float4& v, int k) {
    return reinterpret_cast<float*>(&v)[k];   // k is compile-time after unroll
}

// Pass 1: per-image per-class sum of p^2 (Q) and argmax histogram (Hist).
// Register budget (the round-0..3 lesson): payload x4[19]=76 VGPRs + inv[4]
// + am[4] + transient exp temps ~= 92, fits the 128 cap of bounds(256,4)
// with NO spill and NO remat. q needs no registers: e^2 values live in the
// payload and are dotted with inv0..3 in the epilogue. Histogram state is
// just am0..3; the 19-class ballot runs once at the end.
__global__ __launch_bounds__(BT, 4) void iw_pass1(
    const float* __restrict__ in,   // (N, C, H, W)
    float* __restrict__ Q,          // [N_IMG * C_CLS], pre-zeroed
    int* __restrict__ Hist)         // [N_IMG * C_CLS], pre-zeroed
{
    const int n   = blockIdx.y;
    const int tid = threadIdx.x;
    const int i   = blockIdx.x * BT + tid;       // float4 index in plane
    const float4* base4 = reinterpret_cast<const float4*>(in + (size_t)n * C_CLS * HW);

    // 19 independent 16B/lane loads, all in flight together
    float4 x[C_CLS];
#pragma unroll
    for (int c = 0; c < C_CLS; ++c)
        x[c] = base4[(size_t)c * HW4 + i];

    int   am[4];
    float inv[4];
#pragma unroll
    for (int k = 0; k < 4; ++k) {
        // argmax (first index on ties, matching jnp.argmax) + max
        float m = f4c(x[0], k);
        int   a = 0;
#pragma unroll
        for (int c = 1; c < C_CLS; ++c) {
            float xc = f4c(x[c], k);
            if (xc > m) { m = xc; a = c; }
        }
        am[k] = a;
        // softmax denom; overwrite component k in place with e^2
        float S = 0.0f;
#pragma unroll
        for (int c = 0; c < C_CLS; ++c) {
            float e = __expf(f4c(x[c], k) - m);
            S += e;
            f4c(x[c], k) = e * e;
        }
        inv[k] = __builtin_amdgcn_rcpf(S * S);   // p_c^2 = e^2 * inv
    }

    __shared__ float qs[C_CLS][BT / 4 + 1];   // 19 x 65 floats = 4.9 KB
    __shared__ int   hs[4][C_CLS];

    // per-thread q_c = sum_k e2[c][k]*inv[k]; 2 DPP shuffles; park in LDS
#pragma unroll
    for (int c = 0; c < C_CLS; ++c) {
        float v = x[c].x * inv[0];
        v = fmaf(x[c].y, inv[1], v);
        v = fmaf(x[c].z, inv[2], v);
        v = fmaf(x[c].w, inv[3], v);
        v += __shfl_xor(v, 1, 64);
        v += __shfl_xor(v, 2, 64);
        if ((tid & 3) == 0) qs[c][tid >> 2] = v;
    }

    // histogram via wave ballot: transient scalar counts, no VGPR accumulators
    const int wave = tid >> 6, lane = tid & 63;
#pragma unroll
    for (int c = 0; c < C_CLS; ++c) {
        int cnt = (int)__popcll(__ballot(am[0] == c))
                + (int)__popcll(__ballot(am[1] == c))
                + (int)__popcll(__ballot(am[2] == c))
                + (int)__popcll(__ballot(am[3] == c));
        if (lane == 0) hs[wave][c] = cnt;
    }
    __syncthreads();

    // 152 threads: class c = t>>3, slot s = t&7 sums 8 entries, then 3 shuffles
    if (tid < 8 * C_CLS) {
        const int c = tid >> 3, s = tid & 7;
        float v = 0.0f;
#pragma unroll
        for (int j = 0; j < 8; ++j) v += qs[c][s * 8 + j];
        v += __shfl_xor(v, 1, 64);
        v += __shfl_xor(v, 2, 64);
        v += __shfl_xor(v, 4, 64);
        if (s == 0) atomicAdd(&Q[n * C_CLS + c], v);
    }
    if (tid < C_CLS) {
        int hv = hs[0][tid] + hs[1][tid] + hs[2][tid] + hs[3][tid];
        atomicAdd(&Hist[n * C_CLS + tid], hv);
    }
}

// Pass 2: weights from histogram, dot with Q, write scalar mean loss.
__global__ __launch_bounds__(64) void iw_pass2(
    const float* __restrict__ Q,
    const int* __restrict__ Hist,
    float* __restrict__ out)
{
    const int t = threadIdx.x;
    float loss = 0.0f;
    if (t < N_IMG) {
        float h[C_CLS];
        float hsum = 0.0f;
#pragma unroll
        for (int c = 0; c < C_CLS; ++c) {
            float v = (float)Hist[t * C_CLS + c];
            v = (v == 0.0f) ? 1.0f : v;                  // hist[hist==0] = 1
            h[c] = v;
            hsum += v;                                   // sum AFTER replacement
        }
#pragma unroll
        for (int c = 0; c < C_CLS; ++c) {
            float w = powf(hsum / h[c], RATIO);
            loss = fmaf(w, Q[t * C_CLS + c], loss);
        }
    }
    // reduce the 8 per-image values (lanes 8..63 contribute 0)
    loss += __shfl_xor(loss, 1, 64);
    loss += __shfl_xor(loss, 2, 64);
    loss += __shfl_xor(loss, 4, 64);
    if (t == 0)
        out[0] = -loss / (float)TOTAL_ELEMS;
}

extern "C" void kernel_launch(void* const* d_in, const int* in_sizes, int n_in,
                              void* d_out, int out_size, void* d_ws, size_t ws_size,
                              hipStream_t stream)
{
    const float* in = (const float*)d_in[0];
    float* out = (float*)d_out;

    // workspace layout: Q (float[152]) then Hist (int[152])
    float* Q  = (float*)d_ws;
    int* Hist = (int*)((char*)d_ws + N_IMG * C_CLS * sizeof(float));

    hipMemsetAsync(d_ws, 0, N_IMG * C_CLS * (sizeof(float) + sizeof(int)), stream);

    dim3 grid(BLOCKS_X, N_IMG);
    iw_pass1<<<grid, BT, 0, stream>>>(in, Q, Hist);
    iw_pass2<<<1, 64, 0, stream>>>(Q, Hist, out);
}